// Round 9
// baseline (79.786 us; speedup 1.0000x reference)
//
#include <hip/hip_runtime.h>

// B=8, C=256, Cr=64, S=64.  tb==lr, bt==rl (verified; rounds 1-8 PASS).
//   R0[b,r,w] = (s1 + s0*(w>=1) + s2*(w<=62)) / max(s0+s1+s2,1e-6)
//   h1 scan along w with lam[b,c,w,r]*x ; P = h1*u
//   h2 scan along w with lam[b,c,63-w,63-r]*x ; Q = h2*u[b,c,63-r,w]
//   out = WA@P + WB@Q + b_merge; WAB[cc][o]=w_merge[o,cc]+w_merge[o,cc+512]
// R9: k_prep+k_red+k_ulam fused into k_front (red tile [64k][64px] is complete
// per block -> feed ulam MFMA via LDS, no red2 round-trip; W2T built by 16
// extra blocks). 3 kernels total. Math path value-identical to R8.

typedef __attribute__((ext_vector_type(8))) short short8b;
typedef __attribute__((ext_vector_type(4))) float f32x4;
typedef __attribute__((ext_vector_type(2))) unsigned int uint2v;
typedef __attribute__((ext_vector_type(4))) unsigned int uint4v;

__device__ __forceinline__ unsigned short bf16_rne(float v) {
  unsigned u = __float_as_uint(v);
  unsigned r = u + 0x7FFF + ((u >> 16) & 1);
  return (unsigned short)(r >> 16);
}
__device__ __forceinline__ float bf16_f(unsigned short h) {
  return __uint_as_float((unsigned)h << 16);
}

// 8 tr_reads (4 addresses x {0, +128B}) + in-asm drain; outputs safe to copy.
#define TR_READ8(q0,q1,q2,q3,q4,q5,q6,q7,va0,va1,va2,va3)                      \
  asm volatile("ds_read_b64_tr_b16 %0, %8\n\t"                                 \
               "ds_read_b64_tr_b16 %1, %8 offset:128\n\t"                      \
               "ds_read_b64_tr_b16 %2, %9\n\t"                                 \
               "ds_read_b64_tr_b16 %3, %9 offset:128\n\t"                      \
               "ds_read_b64_tr_b16 %4, %10\n\t"                                \
               "ds_read_b64_tr_b16 %5, %10 offset:128\n\t"                     \
               "ds_read_b64_tr_b16 %6, %11\n\t"                                \
               "ds_read_b64_tr_b16 %7, %11 offset:128\n\t"                     \
               "s_waitcnt lgkmcnt(0)"                                          \
               : "=&v"(q0), "=&v"(q1), "=&v"(q2), "=&v"(q3),                   \
                 "=&v"(q4), "=&v"(q5), "=&v"(q6), "=&v"(q7)                    \
               : "v"(va0), "v"(va1), "v"(va2), "v"(va3))

// fused: red GEMM -> R0 -> ulam MFMA (u,lam bf16 out); extra blocks build W2T
__global__ __launch_bounds__(256) void k_front(const float* __restrict__ x,
    const float* __restrict__ w_red, const float* __restrict__ b_red,
    const float* __restrict__ w_wt, const float* __restrict__ b_wt,
    const float* __restrict__ w_u, const float* __restrict__ b_u,
    const float* __restrict__ w_lam, const float* __restrict__ b_lam,
    const float* __restrict__ w_merge,
    unsigned short* __restrict__ u, unsigned short* __restrict__ lam,
    float* __restrict__ R0, unsigned short* __restrict__ W2T) {
  const int t = threadIdx.x;
  if (blockIdx.x >= 64) {                      // W2T builder blocks
    int e = (blockIdx.x - 64) * 8 + blockIdx.y;  // 0..15
#pragma unroll
    for (int i = 0; i < 32; i++) {
      int m = e * 8192 + i * 256 + t;          // m = o*512 + cc
      int o = m >> 9, cc = m & 511;
      float v = w_merge[o * 1024 + cc] + w_merge[o * 1024 + cc + 512];
      W2T[m] = bf16_rne(v);
    }
    return;
  }
  __shared__ float xs[64][68];                 // x tiles; later WL (bf16 weights)
  __shared__ float ws[64][68];                 // w_red tiles; later preS + PL
  unsigned short* WL = (unsigned short*)&xs[0][0];            // 9216 B
  float* preS = &ws[0][0];                                    // 768 B
  unsigned short* PL = (unsigned short*)((char*)&ws[0][0] + 4096);  // 8192 B
  const int b = blockIdx.y;
  const int px0 = blockIdx.x * 64;
  const int pxg = t & 15, mg = t >> 4;

  // ---- main red GEMM: K=256 in 4 chunks ----
  float acc[4][4] = {};
  for (int ch = 0; ch < 4; ch++) {
    int c0 = ch * 64;
#pragma unroll
    for (int i = 0; i < 4; i++) {
      int idx4 = i * 256 + t;
      int kk = idx4 >> 4, j4 = idx4 & 15;
      *(float4*)&xs[kk][j4 * 4] =
          *(const float4*)(x + ((size_t)b << 20) + ((size_t)(c0 + kk) << 12) + px0 + j4 * 4);
    }
    {  // transpose-stage w_red: ws[c-within-chunk][m] = w_red[m*256 + c0 + c]
      int row = t >> 2, q = t & 3;
      const float* wp = w_red + row * 256 + c0 + q * 16;
      float4 va = *(const float4*)(wp);
      float4 vb = *(const float4*)(wp + 4);
      float4 vc = *(const float4*)(wp + 8);
      float4 vd = *(const float4*)(wp + 12);
      float tmp[16] = {va.x, va.y, va.z, va.w, vb.x, vb.y, vb.z, vb.w,
                       vc.x, vc.y, vc.z, vc.w, vd.x, vd.y, vd.z, vd.w};
#pragma unroll
      for (int jj = 0; jj < 16; jj++) ws[q * 16 + jj][row] = tmp[jj];
    }
    __syncthreads();
#pragma unroll 8
    for (int kk = 0; kk < 64; kk++) {
      float4 a = *(float4*)&xs[kk][pxg * 4];
      float4 w = *(float4*)&ws[kk][mg * 4];
      float aa[4] = {a.x, a.y, a.z, a.w}, wv[4] = {w.x, w.y, w.z, w.w};
#pragma unroll
      for (int j = 0; j < 4; j++)
#pragma unroll
        for (int i = 0; i < 4; i++) acc[j][i] = fmaf(wv[j], aa[i], acc[j][i]);
    }
    __syncthreads();
  }
  // ---- epilogue: fp32 red -> xs (for R0); bf16 red -> PL (MFMA staging) ----
#pragma unroll
  for (int j = 0; j < 4; j++) {
    int k = mg * 4 + j;
    float bv = b_red[k];
    float v[4];
#pragma unroll
    for (int i = 0; i < 4; i++) v[i] = acc[j][i] + bv;
    float* d = &xs[k][pxg * 4];
    d[0] = v[0]; d[1] = v[1]; d[2] = v[2]; d[3] = v[3];
#pragma unroll
    for (int i = 0; i < 4; i++) {
      int pxl = pxg * 4 + i;
      int off = ((pxl >> 4) << 10) + ((k >> 2) << 6) + ((k & 3) << 4) + (pxl & 15);
      PL[off] = bf16_rne(v[i]);
    }
  }
  __syncthreads();
  // ---- R0: pre = w_wt @ red ----
  if (t < 192) {
    int j = t >> 6, px = t & 63;
    float a = b_wt[j];
    for (int kk = 0; kk < 64; kk++) a = fmaf(w_wt[j * 64 + kk], xs[kk][px], a);
    preS[j * 64 + px] = a;
  }
  __syncthreads();
  if (t < 64) {
    float s0 = 1.f / (1.f + __expf(-preS[t]));
    float s1 = 1.f / (1.f + __expf(-preS[64 + t]));
    float s2 = 1.f / (1.f + __expf(-preS[128 + t]));
    int w = t;   // px0 multiple of 64: tile = one image row
    float num = s1 + (w >= 1 ? s0 : 0.f) + (w <= 62 ? s2 : 0.f);
    R0[((size_t)b << 12) + px0 + t] = num / fmaxf(s0 + s1 + s2, 1e-6f);
  }
  // ---- ulam MFMA: 8 chunks of 64 m (4 u, 4 lam), K=64 ----
  const int lane = t & 63;
  const int ln15 = lane & 15, lg = lane >> 4;
  const int wv = t >> 6;                       // wave owns 16 m rows per chunk
  const unsigned pbase = (unsigned)(size_t)PL;
  const unsigned vab = pbase + (unsigned)(lg * 256 + ln15 * 8);
  for (int mc = 0; mc < 8; ++mc) {
    const float* Wsrc = (mc < 4) ? w_u : w_lam;
    const float* bias = (mc < 4) ? b_u : b_lam;
    unsigned short* dst = (mc < 4) ? u : lam;
    int m0 = (mc & 3) * 64;
    __syncthreads();                           // prior MFMA reads of WL done
    {  // stage WL[row][k] = bf16(W[(m0+row)*64 + k])
      int row = t >> 2, q = t & 3;
      const float* wp = Wsrc + (m0 + row) * 64 + q * 16;
      float4 va = *(const float4*)(wp);
      float4 vb = *(const float4*)(wp + 4);
      float4 vc = *(const float4*)(wp + 8);
      float4 vd = *(const float4*)(wp + 12);
      float tmp[16] = {va.x, va.y, va.z, va.w, vb.x, vb.y, vb.z, vb.w,
                       vc.x, vc.y, vc.z, vc.w, vd.x, vd.y, vd.z, vd.w};
      unsigned short* dw = &WL[row * 72 + q * 16];
#pragma unroll
      for (int jj = 0; jj < 16; jj++) dw[jj] = bf16_rne(tmp[jj]);
    }
    __syncthreads();
    f32x4 ac[4];
#pragma unroll
    for (int j = 0; j < 4; j++) ac[j] = (f32x4){0.f, 0.f, 0.f, 0.f};
#pragma unroll
    for (int kstep = 0; kstep < 2; kstep++) {
      short8b am = *(const short8b*)&WL[(wv * 16 + ln15) * 72 + kstep * 32 + lg * 8];
      unsigned va0 = vab + kstep * 1024;
      unsigned va1 = va0 + 2048, va2 = va0 + 4096, va3 = va0 + 6144;
      uint2v q0, q1, q2, q3, q4, q5, q6, q7;
      TR_READ8(q0, q1, q2, q3, q4, q5, q6, q7, va0, va1, va2, va3);
      __builtin_amdgcn_sched_barrier(0);
      uint4v bu[4] = {(uint4v){q0.x, q0.y, q1.x, q1.y}, (uint4v){q2.x, q2.y, q3.x, q3.y},
                      (uint4v){q4.x, q4.y, q5.x, q5.y}, (uint4v){q6.x, q6.y, q7.x, q7.y}};
#pragma unroll
      for (int j = 0; j < 4; j++)
        ac[j] = __builtin_amdgcn_mfma_f32_16x16x32_bf16(
            am, __builtin_bit_cast(short8b, bu[j]), ac[j], 0, 0, 0);
    }
    int orow = wv * 16 + lg * 4;
    float bm[4];
#pragma unroll
    for (int r = 0; r < 4; r++) bm[r] = bias[m0 + orow + r];
#pragma unroll
    for (int j = 0; j < 4; j++) {
      int pxc = px0 + j * 16 + ln15;
#pragma unroll
      for (int r = 0; r < 4; r++)
        dst[((size_t)b << 20) + ((size_t)(m0 + orow + r) << 12) + pxc] =
            bf16_rne(ac[j][r] + bm[r]);
    }
  }
}

// chunk-parallel dual scan; block=(c,b), 256 thr = 64 r x 4 w-chunks
__global__ __launch_bounds__(256) void k_scan(const float* __restrict__ x,
    const unsigned short* __restrict__ lam, const unsigned short* __restrict__ u,
    const float* __restrict__ R0, unsigned short* __restrict__ P2,
    unsigned short* __restrict__ Q2) {
  __shared__ __align__(16) char smem[20224];
  float* lamS = (float*)smem;                 // [64][65] f32 (pass 1)
  unsigned* outS = (unsigned*)smem;           // 2 x [64][33] u32 (pass 2)
  float* fixS = (float*)(smem + 16896);       // [64][13] f32
  const int t = threadIdx.x;
  const int c = blockIdx.x;
  const int b = blockIdx.y;
  const size_t ibase = ((size_t)b << 20) + ((size_t)c << 12);

  {
    const unsigned short* lp = lam + ibase;
#pragma unroll
    for (int i = 0; i < 2; i++) {
      int unit = i * 256 + t;                 // 512 units of 8 ushorts
      int row = unit >> 3, c8 = unit & 7;
      short8b v = *(const short8b*)(lp + row * 64 + c8 * 8);
      float* d = &lamS[row * 65 + c8 * 8];
#pragma unroll
      for (int j = 0; j < 8; j++) d[j] = bf16_f((unsigned short)v[j]);
    }
  }
  const int r = t & 63;
  const int qc = __builtin_amdgcn_readfirstlane(t >> 6);  // w-chunk, wave-uniform
  float xr[16], R[16];
  {
    const float* xp = x + ibase + (r << 6) + (qc << 4);
    const float* rp = R0 + ((size_t)b << 12) + (r << 6) + (qc << 4);
#pragma unroll
    for (int i = 0; i < 4; i++) {
      float4 v = *(const float4*)(xp + i * 4);
      xr[i * 4] = v.x; xr[i * 4 + 1] = v.y; xr[i * 4 + 2] = v.z; xr[i * 4 + 3] = v.w;
      float4 w = *(const float4*)(rp + i * 4);
      R[i * 4] = w.x; R[i * 4 + 1] = w.y; R[i * 4 + 2] = w.z; R[i * 4 + 3] = w.w;
    }
  }
  __syncthreads();
  float g1[16], g2[16];
  float A = 1.f, B1 = 0.f, B2 = 0.f;
#pragma unroll
  for (int j = 0; j < 16; j++) {
    int w = (qc << 4) + j;
    float l1 = lamS[w * 65 + r];
    float l2 = lamS[(63 - w) * 65 + (63 - r)];
    g1[j] = l1 * xr[j];
    g2[j] = l2 * xr[j];
    A *= R[j];
    B1 = fmaf(B1, R[j], g1[j]);
    B2 = fmaf(B2, R[j], g2[j]);
  }
  __syncthreads();                       // lamS dead
  fixS[r * 13 + qc * 3 + 0] = A;
  fixS[r * 13 + qc * 3 + 1] = B1;
  fixS[r * 13 + qc * 3 + 2] = B2;
  __syncthreads();
  float h1 = 0.f, h2 = 0.f;
  for (int p = 0; p < qc; p++) {         // wave-uniform trip count
    float Ap  = fixS[r * 13 + p * 3 + 0];
    float Bp1 = fixS[r * 13 + p * 3 + 1];
    float Bp2 = fixS[r * 13 + p * 3 + 2];
    h1 = fmaf(h1, Ap, Bp1);
    h2 = fmaf(h2, Ap, Bp2);
  }
  float ur[16], fr[16];
  {
    const unsigned short* up = u + ibase + (r << 6) + (qc << 4);
    const unsigned short* fp = u + ibase + ((size_t)(63 - r) << 6) + (qc << 4);
    short8b u0 = *(const short8b*)(up);
    short8b u1 = *(const short8b*)(up + 8);
    short8b f0 = *(const short8b*)(fp);
    short8b f1 = *(const short8b*)(fp + 8);
#pragma unroll
    for (int j = 0; j < 8; j++) {
      ur[j] = bf16_f((unsigned short)u0[j]); ur[8 + j] = bf16_f((unsigned short)u1[j]);
      fr[j] = bf16_f((unsigned short)f0[j]); fr[8 + j] = bf16_f((unsigned short)f1[j]);
    }
  }
#pragma unroll
  for (int j2 = 0; j2 < 8; j2++) {
    int j = j2 * 2;
    h1 = fmaf(h1, R[j], g1[j]);         float p0 = h1 * ur[j];
    h2 = fmaf(h2, R[j], g2[j]);         float q0 = h2 * fr[j];
    h1 = fmaf(h1, R[j + 1], g1[j + 1]); float p1 = h1 * ur[j + 1];
    h2 = fmaf(h2, R[j + 1], g2[j + 1]); float q1 = h2 * fr[j + 1];
    int ob = r * 33 + (qc << 3) + j2;
    outS[ob]        = (unsigned)bf16_rne(p0) | ((unsigned)bf16_rne(p1) << 16);
    outS[2112 + ob] = (unsigned)bf16_rne(q0) | ((unsigned)bf16_rne(q1) << 16);
  }
  __syncthreads();
#pragma unroll
  for (int i = 0; i < 4; i++) {
    int flat4 = i * 256 + t;
    int s = flat4 >> 9;
    int rem = flat4 & 511;
    int row = rem >> 3, c8 = rem & 7;
    const unsigned* ls = &outS[s * 2112 + row * 33 + c8 * 4];
    uint4 v = make_uint4(ls[0], ls[1], ls[2], ls[3]);
    unsigned short* base = (s == 0) ? P2 : Q2;
    size_t off = ((size_t)(b * 256 + c)) * 4096 + row * 64 + c8 * 8;
    *(uint4*)(base + off) = v;
  }
}

// MFMA merge: out[b,o,px] = sum_{k'=0..511} W2T[o][k'] * A[k'][px] + b_merge[o]
__global__ __launch_bounds__(256) void k_merge(
    const unsigned short* __restrict__ P2, const unsigned short* __restrict__ Q2,
    const unsigned short* __restrict__ W2T, const float* __restrict__ b_merge,
    float* __restrict__ out) {
  __shared__ __align__(16) unsigned short WL[256 * 72];  // [o][k 64 + pad 8]
  __shared__ __align__(16) unsigned short PL[4096];      // [pxb 4][kb4 16][4][16]
  const int t = threadIdx.x;
  const int px0 = blockIdx.x * 64;
  const int b = blockIdx.y;
  const int lane = t & 63;
  const int ln15 = lane & 15, lg = lane >> 4;
  const int ow = (t >> 6) * 64;                    // wave owns 64 o rows

  const unsigned short* P2b = P2 + (size_t)b * 256 * 4096;
  const unsigned short* Q2b = Q2 + (size_t)b * 256 * 4096;

  f32x4 acc[4][4];
#pragma unroll
  for (int i = 0; i < 4; i++)
#pragma unroll
    for (int j = 0; j < 4; j++) acc[i][j] = (f32x4){0.f, 0.f, 0.f, 0.f};

  short8b wreg[8], preg[2];
#pragma unroll
  for (int i = 0; i < 8; i++) {
    int unit = i * 256 + t, wrow = unit >> 3, wp = unit & 7;
    wreg[i] = *(const short8b*)(W2T + (size_t)wrow * 512 + wp * 8);
  }
#pragma unroll
  for (int i = 0; i < 2; i++) {
    int unit = i * 256 + t, kk = unit >> 3, ap = unit & 7;
    preg[i] = *(const short8b*)(P2b + (size_t)kk * 4096 + px0 + ap * 8);
  }

  const unsigned pbase = (unsigned)(size_t)(&PL[0]);
  const unsigned vab = pbase + (unsigned)(lg * 256 + ln15 * 8);

  for (int it = 0; it < 8; ++it) {
    __syncthreads();
#pragma unroll
    for (int i = 0; i < 8; i++) {
      int unit = i * 256 + t, wrow = unit >> 3, wp = unit & 7;
      *(short8b*)&WL[wrow * 72 + wp * 8] = wreg[i];
    }
#pragma unroll
    for (int i = 0; i < 2; i++) {
      int unit = i * 256 + t, kk = unit >> 3, ap = unit & 7;
      int off = ((ap >> 1) << 10) + ((kk >> 2) << 6) + ((kk & 3) << 4) + (ap & 1) * 8;
      *(short8b*)&PL[off] = preg[i];
    }
    __syncthreads();
    if (it < 7) {
      int nt = it + 1;
#pragma unroll
      for (int i = 0; i < 8; i++) {
        int unit = i * 256 + t, wrow = unit >> 3, wp = unit & 7;
        wreg[i] = *(const short8b*)(W2T + (size_t)wrow * 512 + nt * 64 + wp * 8);
      }
      const unsigned short* ps = (nt < 4) ? P2b : Q2b;
      int row0 = (nt & 3) * 64;
#pragma unroll
      for (int i = 0; i < 2; i++) {
        int unit = i * 256 + t, kk = unit >> 3, ap = unit & 7;
        preg[i] = *(const short8b*)(ps + (size_t)(row0 + kk) * 4096 + px0 + ap * 8);
      }
    }
#pragma unroll
    for (int kstep = 0; kstep < 2; kstep++) {
      short8b am[4];
#pragma unroll
      for (int i = 0; i < 4; i++)
        am[i] = *(const short8b*)&WL[(ow + i * 16 + ln15) * 72 + kstep * 32 + lg * 8];
      unsigned va0 = vab + kstep * 1024;
      unsigned va1 = va0 + 2048, va2 = va0 + 4096, va3 = va0 + 6144;
      uint2v q0, q1, q2, q3, q4, q5, q6, q7;
      TR_READ8(q0, q1, q2, q3, q4, q5, q6, q7, va0, va1, va2, va3);
      __builtin_amdgcn_sched_barrier(0);
      uint4v bu[4] = {(uint4v){q0.x, q0.y, q1.x, q1.y}, (uint4v){q2.x, q2.y, q3.x, q3.y},
                      (uint4v){q4.x, q4.y, q5.x, q5.y}, (uint4v){q6.x, q6.y, q7.x, q7.y}};
#pragma unroll
      for (int i = 0; i < 4; i++)
#pragma unroll
        for (int j = 0; j < 4; j++)
          acc[i][j] = __builtin_amdgcn_mfma_f32_16x16x32_bf16(
              am[i], __builtin_bit_cast(short8b, bu[j]), acc[i][j], 0, 0, 0);
    }
  }

#pragma unroll
  for (int i = 0; i < 4; i++) {
    int orow = ow + i * 16 + lg * 4;
    float bm[4];
#pragma unroll
    for (int r = 0; r < 4; r++) bm[r] = b_merge[orow + r];
#pragma unroll
    for (int j = 0; j < 4; j++) {
      int pxc = px0 + j * 16 + ln15;
      float* op = out + ((size_t)b << 20) + ((size_t)orow << 12) + pxc;
#pragma unroll
      for (int r = 0; r < 4; r++) op[(size_t)r << 12] = acc[i][j][r] + bm[r];
    }
  }
}

extern "C" void kernel_launch(void* const* d_in, const int* in_sizes, int n_in,
                              void* d_out, int out_size, void* d_ws, size_t ws_size,
                              hipStream_t stream) {
  const float* x       = (const float*)d_in[0];
  const float* w_red   = (const float*)d_in[1];
  const float* b_red   = (const float*)d_in[2];
  const float* w_u     = (const float*)d_in[3];
  const float* b_u     = (const float*)d_in[4];
  const float* w_lam   = (const float*)d_in[5];
  const float* b_lam   = (const float*)d_in[6];
  const float* w_wt    = (const float*)d_in[7];
  const float* b_wt    = (const float*)d_in[8];
  const float* w_merge = (const float*)d_in[9];
  const float* b_merge = (const float*)d_in[10];
  float* out = (float*)d_out;
  char* wsb = (char*)d_ws;

  unsigned short* u   = (unsigned short*)(wsb);              // 8388608 us
  unsigned short* lam = (unsigned short*)(wsb + 16777216);   // 8388608 us
  float* R0           = (float*)(wsb + 33554432);            // 32768 f
  unsigned short* W2T = (unsigned short*)(wsb + 33685504);   // 131072 us
  unsigned short* P2  = (unsigned short*)(wsb + 33947648);   // 8388608 us
  unsigned short* Q2  = (unsigned short*)(wsb + 50724864);   // 8388608 us (end ~67.5MB)

  hipLaunchKernelGGL(k_front, dim3(66, 8),  dim3(256), 0, stream,
                     x, w_red, b_red, w_wt, b_wt, w_u, b_u, w_lam, b_lam, w_merge,
                     u, lam, R0, W2T);
  hipLaunchKernelGGL(k_scan,  dim3(256, 8), dim3(256), 0, stream, x, lam, u, R0, P2, Q2);
  hipLaunchKernelGGL(k_merge, dim3(64, 8),  dim3(256), 0, stream, P2, Q2, W2T, b_merge, out);
}

// Round 10
// 78.625 us; speedup vs baseline: 1.0148x; 1.0148x over previous
//
#include <hip/hip_runtime.h>

// B=8, C=256, Cr=64, S=64.  tb==lr, bt==rl (verified; rounds 1-8 PASS).
//   R0[b,r,w] = (s1 + s0*(w>=1) + s2*(w<=62)) / max(s0+s1+s2,1e-6)
//   h1 scan along w with lam[b,c,w,r]*x ; P = h1*u
//   h2 scan along w with lam[b,c,63-w,63-r]*x ; Q = h2*u[b,c,63-r,w]
//   out = WA@P + WB@Q + b_merge; WAB[cc][o]=w_merge[o,cc]+w_merge[o,cc+512]
// R10: revert R9 fusion (bank-conflict + serialization regression). R8
// structure, but k_prep folded into k_red: work blocks transpose w_red in-LDS
// conflict-free (lane addrs = const+m -> 2-way = free); 64 extra blocks build
// wu2/wlam2/W2T (consumed only by later kernels). Math bit-identical to R8.

typedef __attribute__((ext_vector_type(8))) short short8b;
typedef __attribute__((ext_vector_type(4))) float f32x4;
typedef __attribute__((ext_vector_type(2))) unsigned int uint2v;
typedef __attribute__((ext_vector_type(4))) unsigned int uint4v;

__device__ __forceinline__ unsigned short bf16_rne(float v) {
  unsigned u = __float_as_uint(v);
  unsigned r = u + 0x7FFF + ((u >> 16) & 1);
  return (unsigned short)(r >> 16);
}
__device__ __forceinline__ float bf16_f(unsigned short h) {
  return __uint_as_float((unsigned)h << 16);
}

// 8 tr_reads (4 addresses x {0, +128B}) + in-asm drain; outputs safe to copy.
#define TR_READ8(q0,q1,q2,q3,q4,q5,q6,q7,va0,va1,va2,va3)                      \
  asm volatile("ds_read_b64_tr_b16 %0, %8\n\t"                                 \
               "ds_read_b64_tr_b16 %1, %8 offset:128\n\t"                      \
               "ds_read_b64_tr_b16 %2, %9\n\t"                                 \
               "ds_read_b64_tr_b16 %3, %9 offset:128\n\t"                      \
               "ds_read_b64_tr_b16 %4, %10\n\t"                                \
               "ds_read_b64_tr_b16 %5, %10 offset:128\n\t"                     \
               "ds_read_b64_tr_b16 %6, %11\n\t"                                \
               "ds_read_b64_tr_b16 %7, %11 offset:128\n\t"                     \
               "s_waitcnt lgkmcnt(0)"                                          \
               : "=&v"(q0), "=&v"(q1), "=&v"(q2), "=&v"(q3),                   \
                 "=&v"(q4), "=&v"(q5), "=&v"(q6), "=&v"(q7)                    \
               : "v"(va0), "v"(va1), "v"(va2), "v"(va3))

// red[b,m,px] (bf16) = sum_c w_red[m,c]*x[b,c,px] + b_red[m]; fused R0 epilogue.
// blockIdx.x >= 64: prep blocks build wu2/wlam2/W2T (no intra-kernel consumer).
__global__ __launch_bounds__(256) void k_red(const float* __restrict__ x,
    const float* __restrict__ w_red, const float* __restrict__ b_red,
    const float* __restrict__ w_wt, const float* __restrict__ b_wt,
    const float* __restrict__ w_u, const float* __restrict__ w_lam,
    const float* __restrict__ w_merge,
    unsigned short* __restrict__ red2, float* __restrict__ R0,
    unsigned short* __restrict__ wu2, unsigned short* __restrict__ wlam2,
    unsigned short* __restrict__ W2T) {
  const int t = threadIdx.x;
  if (blockIdx.x >= 64) {                       // ---- prep blocks ----
    int e = (blockIdx.x - 64) * 8 + blockIdx.y; // 0..63
#pragma unroll
    for (int i = 0; i < 10; i++) {
      int flat = e * 2560 + i * 256 + t;        // < 163840
      if (flat < 16384) {
        wu2[flat] = bf16_rne(w_u[flat]);        // [m][k] natural layout
      } else if (flat < 32768) {
        wlam2[flat - 16384] = bf16_rne(w_lam[flat - 16384]);
      } else {
        int mm = flat - 32768;                  // mm = o*512 + cc
        int o = mm >> 9, cc = mm & 511;
        float v = w_merge[o * 1024 + cc] + w_merge[o * 1024 + cc + 512];
        W2T[mm] = bf16_rne(v);
      }
    }
    return;
  }
  __shared__ float xs[64][68];
  __shared__ float ws[64][68];                  // ws[c][m], == R8's wredT tile
  int b = blockIdx.y;
  int px0 = blockIdx.x * 64;
  int pxg = t & 15, mg = t >> 4;
  const int tm = t & 63, tcg = t >> 6;          // transpose staging roles
  float acc[4][4] = {};
  for (int ch = 0; ch < 4; ch++) {
    int c0 = ch * 64;
#pragma unroll
    for (int i = 0; i < 4; i++) {
      int idx4 = i * 256 + t;
      int kk = idx4 >> 4, j4 = idx4 & 15;
      *(float4*)&xs[kk][j4 * 4] =
          *(const float4*)(x + ((size_t)b << 20) + ((size_t)kk + c0 << 12) + px0 + j4 * 4);
    }
    // conflict-free w_red transpose: lane tm handles row m=tm, 16 c's
#pragma unroll
    for (int s = 0; s < 4; s++) {
      int cc = tcg * 16 + s * 4;
      float4 v = *(const float4*)(w_red + tm * 256 + c0 + cc);
      ws[cc + 0][tm] = v.x; ws[cc + 1][tm] = v.y;
      ws[cc + 2][tm] = v.z; ws[cc + 3][tm] = v.w;
    }
    __syncthreads();
#pragma unroll 8
    for (int kk = 0; kk < 64; kk++) {
      float4 a = *(float4*)&xs[kk][pxg * 4];
      float4 w = *(float4*)&ws[kk][mg * 4];
      float aa[4] = {a.x, a.y, a.z, a.w}, wv[4] = {w.x, w.y, w.z, w.w};
#pragma unroll
      for (int j = 0; j < 4; j++)
#pragma unroll
        for (int i = 0; i < 4; i++) acc[j][i] = fmaf(wv[j], aa[i], acc[j][i]);
    }
    __syncthreads();
  }
  // store bf16 red + stage fp32 red (with bias) into xs for R0
#pragma unroll
  for (int j = 0; j < 4; j++) {
    int m = mg * 4 + j;
    float bv = b_red[m];
    float v0 = acc[j][0] + bv, v1 = acc[j][1] + bv, v2 = acc[j][2] + bv, v3 = acc[j][3] + bv;
    ushort4 uv = make_ushort4(bf16_rne(v0), bf16_rne(v1), bf16_rne(v2), bf16_rne(v3));
    *(ushort4*)(red2 + ((size_t)b << 18) + ((size_t)m << 12) + px0 + pxg * 4) = uv;
    float* d = &xs[m][pxg * 4];
    d[0] = v0; d[1] = v1; d[2] = v2; d[3] = v3;
  }
  __syncthreads();
  float* preS = &ws[0][0];
  if (t < 192) {
    int j = t >> 6, px = t & 63;
    float a = b_wt[j];
    for (int kk = 0; kk < 64; kk++) a = fmaf(w_wt[j * 64 + kk], xs[kk][px], a);
    preS[j * 64 + px] = a;
  }
  __syncthreads();
  if (t < 64) {
    float s0 = 1.f / (1.f + __expf(-preS[t]));
    float s1 = 1.f / (1.f + __expf(-preS[64 + t]));
    float s2 = 1.f / (1.f + __expf(-preS[128 + t]));
    int w = t;   // px0 is a multiple of 64, tile = one image row
    float num = s1 + (w >= 1 ? s0 : 0.f) + (w <= 62 ? s2 : 0.f);
    R0[((size_t)b << 12) + px0 + t] = num / fmaxf(s0 + s1 + s2, 1e-6f);
  }
}

// MFMA u/lam: dst[b,m,px] = bf16( sum_k W[m,k]*red2[b,k,px] + bias[m] )
// block: 256 m x 64 px, K=64; blockIdx.z: 0 -> u, 1 -> lam
__global__ __launch_bounds__(256) void k_ulam(const unsigned short* __restrict__ red2,
    const unsigned short* __restrict__ wu2, const float* __restrict__ b_u,
    const unsigned short* __restrict__ wlam2, const float* __restrict__ b_lam,
    unsigned short* __restrict__ u, unsigned short* __restrict__ lam) {
  __shared__ __align__(16) unsigned short WL[256 * 72];  // [m][k 64 + pad 8]
  __shared__ __align__(16) unsigned short PL[4096];      // [pxb 4][kb4 16][4][16]
  const int t = threadIdx.x;
  const int px0 = blockIdx.x * 64;
  const int b = blockIdx.y;
  const int mt = blockIdx.z;
  const unsigned short* Wsrc = (mt == 0) ? wu2 : wlam2;
  const float* bias = (mt == 0) ? b_u : b_lam;
  unsigned short* dst = (mt == 0) ? u : lam;
  const unsigned short* red2b = red2 + ((size_t)b << 18);
  const int lane = t & 63;
  const int ln15 = lane & 15, lg = lane >> 4;
  const int ow = (t >> 6) * 64;                    // wave owns 64 m rows

#pragma unroll
  for (int i = 0; i < 8; i++) {
    int unit = i * 256 + t, wrow = unit >> 3, wp = unit & 7;
    *(short8b*)&WL[wrow * 72 + wp * 8] = *(const short8b*)(Wsrc + wrow * 64 + wp * 8);
  }
#pragma unroll
  for (int i = 0; i < 2; i++) {
    int unit = i * 256 + t, kk = unit >> 3, ap = unit & 7;
    int off = ((ap >> 1) << 10) + ((kk >> 2) << 6) + ((kk & 3) << 4) + (ap & 1) * 8;
    *(short8b*)&PL[off] = *(const short8b*)(red2b + (size_t)kk * 4096 + px0 + ap * 8);
  }
  __syncthreads();

  f32x4 acc[4][4];
#pragma unroll
  for (int i = 0; i < 4; i++)
#pragma unroll
    for (int j = 0; j < 4; j++) acc[i][j] = (f32x4){0.f, 0.f, 0.f, 0.f};

  const unsigned pbase = (unsigned)(size_t)(&PL[0]);
  const unsigned vab = pbase + (unsigned)(lg * 256 + ln15 * 8);
#pragma unroll
  for (int kstep = 0; kstep < 2; kstep++) {
    short8b am[4];
#pragma unroll
    for (int i = 0; i < 4; i++)
      am[i] = *(const short8b*)&WL[(ow + i * 16 + ln15) * 72 + kstep * 32 + lg * 8];
    unsigned va0 = vab + kstep * 1024;
    unsigned va1 = va0 + 2048, va2 = va0 + 4096, va3 = va0 + 6144;
    uint2v q0, q1, q2, q3, q4, q5, q6, q7;
    TR_READ8(q0, q1, q2, q3, q4, q5, q6, q7, va0, va1, va2, va3);
    __builtin_amdgcn_sched_barrier(0);
    uint4v bu[4] = {(uint4v){q0.x, q0.y, q1.x, q1.y}, (uint4v){q2.x, q2.y, q3.x, q3.y},
                    (uint4v){q4.x, q4.y, q5.x, q5.y}, (uint4v){q6.x, q6.y, q7.x, q7.y}};
#pragma unroll
    for (int i = 0; i < 4; i++)
#pragma unroll
      for (int j = 0; j < 4; j++)
        acc[i][j] = __builtin_amdgcn_mfma_f32_16x16x32_bf16(
            am[i], __builtin_bit_cast(short8b, bu[j]), acc[i][j], 0, 0, 0);
  }

#pragma unroll
  for (int i = 0; i < 4; i++) {
    int orow = ow + i * 16 + lg * 4;
    float bm[4];
#pragma unroll
    for (int r = 0; r < 4; r++) bm[r] = bias[orow + r];
#pragma unroll
    for (int j = 0; j < 4; j++) {
      int pxc = px0 + j * 16 + ln15;
#pragma unroll
      for (int r = 0; r < 4; r++)
        dst[((size_t)b << 20) + ((size_t)(orow + r) << 12) + pxc] =
            bf16_rne(acc[i][j][r] + bm[r]);
    }
  }
}

// chunk-parallel dual scan; block=(c,b), 256 thr = 64 r x 4 w-chunks
__global__ __launch_bounds__(256) void k_scan(const float* __restrict__ x,
    const unsigned short* __restrict__ lam, const unsigned short* __restrict__ u,
    const float* __restrict__ R0, unsigned short* __restrict__ P2,
    unsigned short* __restrict__ Q2) {
  __shared__ __align__(16) char smem[20224];
  float* lamS = (float*)smem;                 // [64][65] f32 (pass 1)
  unsigned* outS = (unsigned*)smem;           // 2 x [64][33] u32 (pass 2)
  float* fixS = (float*)(smem + 16896);       // [64][13] f32
  const int t = threadIdx.x;
  const int c = blockIdx.x;
  const int b = blockIdx.y;
  const size_t ibase = ((size_t)b << 20) + ((size_t)c << 12);

  {
    const unsigned short* lp = lam + ibase;
#pragma unroll
    for (int i = 0; i < 2; i++) {
      int unit = i * 256 + t;                 // 512 units of 8 ushorts
      int row = unit >> 3, c8 = unit & 7;
      short8b v = *(const short8b*)(lp + row * 64 + c8 * 8);
      float* d = &lamS[row * 65 + c8 * 8];
#pragma unroll
      for (int j = 0; j < 8; j++) d[j] = bf16_f((unsigned short)v[j]);
    }
  }
  const int r = t & 63;
  const int qc = __builtin_amdgcn_readfirstlane(t >> 6);  // w-chunk, wave-uniform
  float xr[16], R[16];
  {
    const float* xp = x + ibase + (r << 6) + (qc << 4);
    const float* rp = R0 + ((size_t)b << 12) + (r << 6) + (qc << 4);
#pragma unroll
    for (int i = 0; i < 4; i++) {
      float4 v = *(const float4*)(xp + i * 4);
      xr[i * 4] = v.x; xr[i * 4 + 1] = v.y; xr[i * 4 + 2] = v.z; xr[i * 4 + 3] = v.w;
      float4 w = *(const float4*)(rp + i * 4);
      R[i * 4] = w.x; R[i * 4 + 1] = w.y; R[i * 4 + 2] = w.z; R[i * 4 + 3] = w.w;
    }
  }
  __syncthreads();
  float g1[16], g2[16];
  float A = 1.f, B1 = 0.f, B2 = 0.f;
#pragma unroll
  for (int j = 0; j < 16; j++) {
    int w = (qc << 4) + j;
    float l1 = lamS[w * 65 + r];
    float l2 = lamS[(63 - w) * 65 + (63 - r)];
    g1[j] = l1 * xr[j];
    g2[j] = l2 * xr[j];
    A *= R[j];
    B1 = fmaf(B1, R[j], g1[j]);
    B2 = fmaf(B2, R[j], g2[j]);
  }
  __syncthreads();                       // lamS dead
  fixS[r * 13 + qc * 3 + 0] = A;
  fixS[r * 13 + qc * 3 + 1] = B1;
  fixS[r * 13 + qc * 3 + 2] = B2;
  __syncthreads();
  float h1 = 0.f, h2 = 0.f;
  for (int p = 0; p < qc; p++) {         // wave-uniform trip count
    float Ap  = fixS[r * 13 + p * 3 + 0];
    float Bp1 = fixS[r * 13 + p * 3 + 1];
    float Bp2 = fixS[r * 13 + p * 3 + 2];
    h1 = fmaf(h1, Ap, Bp1);
    h2 = fmaf(h2, Ap, Bp2);
  }
  float ur[16], fr[16];
  {
    const unsigned short* up = u + ibase + (r << 6) + (qc << 4);
    const unsigned short* fp = u + ibase + ((size_t)(63 - r) << 6) + (qc << 4);
    short8b u0 = *(const short8b*)(up);
    short8b u1 = *(const short8b*)(up + 8);
    short8b f0 = *(const short8b*)(fp);
    short8b f1 = *(const short8b*)(fp + 8);
#pragma unroll
    for (int j = 0; j < 8; j++) {
      ur[j] = bf16_f((unsigned short)u0[j]); ur[8 + j] = bf16_f((unsigned short)u1[j]);
      fr[j] = bf16_f((unsigned short)f0[j]); fr[8 + j] = bf16_f((unsigned short)f1[j]);
    }
  }
#pragma unroll
  for (int j2 = 0; j2 < 8; j2++) {
    int j = j2 * 2;
    h1 = fmaf(h1, R[j], g1[j]);         float p0 = h1 * ur[j];
    h2 = fmaf(h2, R[j], g2[j]);         float q0 = h2 * fr[j];
    h1 = fmaf(h1, R[j + 1], g1[j + 1]); float p1 = h1 * ur[j + 1];
    h2 = fmaf(h2, R[j + 1], g2[j + 1]); float q1 = h2 * fr[j + 1];
    int ob = r * 33 + (qc << 3) + j2;
    outS[ob]        = (unsigned)bf16_rne(p0) | ((unsigned)bf16_rne(p1) << 16);
    outS[2112 + ob] = (unsigned)bf16_rne(q0) | ((unsigned)bf16_rne(q1) << 16);
  }
  __syncthreads();
#pragma unroll
  for (int i = 0; i < 4; i++) {
    int flat4 = i * 256 + t;
    int s = flat4 >> 9;
    int rem = flat4 & 511;
    int row = rem >> 3, c8 = rem & 7;
    const unsigned* ls = &outS[s * 2112 + row * 33 + c8 * 4];
    uint4 v = make_uint4(ls[0], ls[1], ls[2], ls[3]);
    unsigned short* base = (s == 0) ? P2 : Q2;
    size_t off = ((size_t)(b * 256 + c)) * 4096 + row * 64 + c8 * 8;
    *(uint4*)(base + off) = v;
  }
}

// MFMA merge: out[b,o,px] = sum_{k'=0..511} W2T[o][k'] * A[k'][px] + b_merge[o]
__global__ __launch_bounds__(256) void k_merge(
    const unsigned short* __restrict__ P2, const unsigned short* __restrict__ Q2,
    const unsigned short* __restrict__ W2T, const float* __restrict__ b_merge,
    float* __restrict__ out) {
  __shared__ __align__(16) unsigned short WL[256 * 72];  // [o][k 64 + pad 8]
  __shared__ __align__(16) unsigned short PL[4096];      // [pxb 4][kb4 16][4][16]
  const int t = threadIdx.x;
  const int px0 = blockIdx.x * 64;
  const int b = blockIdx.y;
  const int lane = t & 63;
  const int ln15 = lane & 15, lg = lane >> 4;
  const int ow = (t >> 6) * 64;                    // wave owns 64 o rows

  const unsigned short* P2b = P2 + (size_t)b * 256 * 4096;
  const unsigned short* Q2b = Q2 + (size_t)b * 256 * 4096;

  f32x4 acc[4][4];
#pragma unroll
  for (int i = 0; i < 4; i++)
#pragma unroll
    for (int j = 0; j < 4; j++) acc[i][j] = (f32x4){0.f, 0.f, 0.f, 0.f};

  short8b wreg[8], preg[2];
#pragma unroll
  for (int i = 0; i < 8; i++) {
    int unit = i * 256 + t, wrow = unit >> 3, wp = unit & 7;
    wreg[i] = *(const short8b*)(W2T + (size_t)wrow * 512 + wp * 8);
  }
#pragma unroll
  for (int i = 0; i < 2; i++) {
    int unit = i * 256 + t, kk = unit >> 3, ap = unit & 7;
    preg[i] = *(const short8b*)(P2b + (size_t)kk * 4096 + px0 + ap * 8);
  }

  const unsigned pbase = (unsigned)(size_t)(&PL[0]);
  const unsigned vab = pbase + (unsigned)(lg * 256 + ln15 * 8);

  for (int it = 0; it < 8; ++it) {
    __syncthreads();
#pragma unroll
    for (int i = 0; i < 8; i++) {
      int unit = i * 256 + t, wrow = unit >> 3, wp = unit & 7;
      *(short8b*)&WL[wrow * 72 + wp * 8] = wreg[i];
    }
#pragma unroll
    for (int i = 0; i < 2; i++) {
      int unit = i * 256 + t, kk = unit >> 3, ap = unit & 7;
      int off = ((ap >> 1) << 10) + ((kk >> 2) << 6) + ((kk & 3) << 4) + (ap & 1) * 8;
      *(short8b*)&PL[off] = preg[i];
    }
    __syncthreads();
    if (it < 7) {
      int nt = it + 1;
#pragma unroll
      for (int i = 0; i < 8; i++) {
        int unit = i * 256 + t, wrow = unit >> 3, wp = unit & 7;
        wreg[i] = *(const short8b*)(W2T + (size_t)wrow * 512 + nt * 64 + wp * 8);
      }
      const unsigned short* ps = (nt < 4) ? P2b : Q2b;
      int row0 = (nt & 3) * 64;
#pragma unroll
      for (int i = 0; i < 2; i++) {
        int unit = i * 256 + t, kk = unit >> 3, ap = unit & 7;
        preg[i] = *(const short8b*)(ps + (size_t)(row0 + kk) * 4096 + px0 + ap * 8);
      }
    }
#pragma unroll
    for (int kstep = 0; kstep < 2; kstep++) {
      short8b am[4];
#pragma unroll
      for (int i = 0; i < 4; i++)
        am[i] = *(const short8b*)&WL[(ow + i * 16 + ln15) * 72 + kstep * 32 + lg * 8];
      unsigned va0 = vab + kstep * 1024;
      unsigned va1 = va0 + 2048, va2 = va0 + 4096, va3 = va0 + 6144;
      uint2v q0, q1, q2, q3, q4, q5, q6, q7;
      TR_READ8(q0, q1, q2, q3, q4, q5, q6, q7, va0, va1, va2, va3);
      __builtin_amdgcn_sched_barrier(0);
      uint4v bu[4] = {(uint4v){q0.x, q0.y, q1.x, q1.y}, (uint4v){q2.x, q2.y, q3.x, q3.y},
                      (uint4v){q4.x, q4.y, q5.x, q5.y}, (uint4v){q6.x, q6.y, q7.x, q7.y}};
#pragma unroll
      for (int i = 0; i < 4; i++)
#pragma unroll
        for (int j = 0; j < 4; j++)
          acc[i][j] = __builtin_amdgcn_mfma_f32_16x16x32_bf16(
              am[i], __builtin_bit_cast(short8b, bu[j]), acc[i][j], 0, 0, 0);
    }
  }

#pragma unroll
  for (int i = 0; i < 4; i++) {
    int orow = ow + i * 16 + lg * 4;
    float bm[4];
#pragma unroll
    for (int r = 0; r < 4; r++) bm[r] = b_merge[orow + r];
#pragma unroll
    for (int j = 0; j < 4; j++) {
      int pxc = px0 + j * 16 + ln15;
      float* op = out + ((size_t)b << 20) + ((size_t)orow << 12) + pxc;
#pragma unroll
      for (int r = 0; r < 4; r++) op[(size_t)r << 12] = acc[i][j][r] + bm[r];
    }
  }
}

extern "C" void kernel_launch(void* const* d_in, const int* in_sizes, int n_in,
                              void* d_out, int out_size, void* d_ws, size_t ws_size,
                              hipStream_t stream) {
  const float* x       = (const float*)d_in[0];
  const float* w_red   = (const float*)d_in[1];
  const float* b_red   = (const float*)d_in[2];
  const float* w_u     = (const float*)d_in[3];
  const float* b_u     = (const float*)d_in[4];
  const float* w_lam   = (const float*)d_in[5];
  const float* b_lam   = (const float*)d_in[6];
  const float* w_wt    = (const float*)d_in[7];
  const float* b_wt    = (const float*)d_in[8];
  const float* w_merge = (const float*)d_in[9];
  const float* b_merge = (const float*)d_in[10];
  float* out = (float*)d_out;
  char* wsb = (char*)d_ws;

  unsigned short* red2  = (unsigned short*)(wsb);            // 2097152 us
  unsigned short* u     = (unsigned short*)(wsb + 4194304);  // 8388608 us
  unsigned short* lam   = (unsigned short*)(wsb + 20971520); // 8388608 us
  float* R0             = (float*)(wsb + 37748736);          // 32768 f
  unsigned short* wu2   = (unsigned short*)(wsb + 37879808); // 16384 us
  unsigned short* wlam2 = (unsigned short*)(wsb + 37912576); // 16384 us
  unsigned short* W2T   = (unsigned short*)(wsb + 37945344); // 131072 us
  unsigned short* P2    = (unsigned short*)(wsb + 38207488); // 8388608 us
  unsigned short* Q2    = (unsigned short*)(wsb + 54984704); // 8388608 us (end ~72MB)

  hipLaunchKernelGGL(k_red,   dim3(72, 8),    dim3(256), 0, stream, x, w_red, b_red,
                     w_wt, b_wt, w_u, w_lam, w_merge, red2, R0, wu2, wlam2, W2T);
  hipLaunchKernelGGL(k_ulam,  dim3(64, 8, 2), dim3(256), 0, stream, red2, wu2, b_u,
                     wlam2, b_lam, u, lam);
  hipLaunchKernelGGL(k_scan,  dim3(256, 8),   dim3(256), 0, stream, x, lam, u, R0, P2, Q2);
  hipLaunchKernelGGL(k_merge, dim3(64, 8),    dim3(256), 0, stream, P2, Q2, W2T, b_merge, out);
}

// Round 11
// 62.972 us; speedup vs baseline: 1.2670x; 1.2486x over previous
//
#include <hip/hip_runtime.h>

// B=8, C=256, Cr=64, S=64.  tb==lr, bt==rl (verified; rounds 1-10 PASS).
//   R0[b,r,w] = (s1 + s0*(w>=1) + s2*(w<=62)) / max(s0+s1+s2,1e-6)
//   h1 scan along w with lam[b,c,w,r]*x ; P = h1*u
//   h2 scan along w with lam[b,c,63-w,63-r]*x ; Q = h2*u[b,c,63-r,w]
//   out = WA@P + WB@Q + b_merge; WAB[cc][o]=w_merge[o,cc]+w_merge[o,cc+512]
// R11: k_red GEMM -> bf16 MFMA (last fp32-VALU GEMM; ~13us -> ~7us predicted).
// R0 from fp32 MFMA accumulator (input-quantization error only). k_ulam /
// k_scan / k_merge byte-identical to R10.

typedef __attribute__((ext_vector_type(8))) short short8b;
typedef __attribute__((ext_vector_type(4))) float f32x4;
typedef __attribute__((ext_vector_type(2))) unsigned int uint2v;
typedef __attribute__((ext_vector_type(4))) unsigned int uint4v;

__device__ __forceinline__ unsigned short bf16_rne(float v) {
  unsigned u = __float_as_uint(v);
  unsigned r = u + 0x7FFF + ((u >> 16) & 1);
  return (unsigned short)(r >> 16);
}
__device__ __forceinline__ float bf16_f(unsigned short h) {
  return __uint_as_float((unsigned)h << 16);
}
__device__ __forceinline__ short8b cvt8(const float* p) {
  float4 a = *(const float4*)p;
  float4 c = *(const float4*)(p + 4);
  short8b r;
  r[0] = (short)bf16_rne(a.x); r[1] = (short)bf16_rne(a.y);
  r[2] = (short)bf16_rne(a.z); r[3] = (short)bf16_rne(a.w);
  r[4] = (short)bf16_rne(c.x); r[5] = (short)bf16_rne(c.y);
  r[6] = (short)bf16_rne(c.z); r[7] = (short)bf16_rne(c.w);
  return r;
}

// 8 tr_reads (4 addresses x {0, +128B}) + in-asm drain; outputs safe to copy.
#define TR_READ8(q0,q1,q2,q3,q4,q5,q6,q7,va0,va1,va2,va3)                      \
  asm volatile("ds_read_b64_tr_b16 %0, %8\n\t"                                 \
               "ds_read_b64_tr_b16 %1, %8 offset:128\n\t"                      \
               "ds_read_b64_tr_b16 %2, %9\n\t"                                 \
               "ds_read_b64_tr_b16 %3, %9 offset:128\n\t"                      \
               "ds_read_b64_tr_b16 %4, %10\n\t"                                \
               "ds_read_b64_tr_b16 %5, %10 offset:128\n\t"                     \
               "ds_read_b64_tr_b16 %6, %11\n\t"                                \
               "ds_read_b64_tr_b16 %7, %11 offset:128\n\t"                     \
               "s_waitcnt lgkmcnt(0)"                                          \
               : "=&v"(q0), "=&v"(q1), "=&v"(q2), "=&v"(q3),                   \
                 "=&v"(q4), "=&v"(q5), "=&v"(q6), "=&v"(q7)                    \
               : "v"(va0), "v"(va1), "v"(va2), "v"(va3))

// red[b,m,px] = sum_c w_red[m,c]*x[b,c,px] + b_red[m]  (bf16-input MFMA,
// fp32 accum) -> red2 bf16 + R0 fused epilogue from fp32 acc.
// blockIdx.x >= 64: prep blocks build wu2/wlam2/W2T.
__global__ __launch_bounds__(256) void k_red(const float* __restrict__ x,
    const float* __restrict__ w_red, const float* __restrict__ b_red,
    const float* __restrict__ w_wt, const float* __restrict__ b_wt,
    const float* __restrict__ w_u, const float* __restrict__ w_lam,
    const float* __restrict__ w_merge,
    unsigned short* __restrict__ red2, float* __restrict__ R0,
    unsigned short* __restrict__ wu2, unsigned short* __restrict__ wlam2,
    unsigned short* __restrict__ W2T) {
  const int t = threadIdx.x;
  if (blockIdx.x >= 64) {                       // ---- prep blocks ----
    int e = (blockIdx.x - 64) * 8 + blockIdx.y; // 0..63
#pragma unroll
    for (int i = 0; i < 10; i++) {
      int flat = e * 2560 + i * 256 + t;        // < 163840
      if (flat < 16384) {
        wu2[flat] = bf16_rne(w_u[flat]);        // [m][k] natural layout
      } else if (flat < 32768) {
        wlam2[flat - 16384] = bf16_rne(w_lam[flat - 16384]);
      } else {
        int mm = flat - 32768;                  // mm = o*512 + cc
        int o = mm >> 9, cc = mm & 511;
        float v = w_merge[o * 1024 + cc] + w_merge[o * 1024 + cc + 512];
        W2T[mm] = bf16_rne(v);
      }
    }
    return;
  }
  __shared__ float xs[64][68];                        // fp32 red for R0 epilogue
  __shared__ __align__(16) unsigned short WL[64 * 72];  // w_red bf16 [m][k+pad]
  __shared__ __align__(16) unsigned short PL[4096];     // x bf16 tr_read staging
  const int b = blockIdx.y;
  const int px0 = blockIdx.x * 64;
  const int lane = t & 63;
  const int ln15 = lane & 15, lg = lane >> 4;
  const int wv = t >> 6;                        // wave owns 16 m rows
  const int wrow = t >> 3 & 63, wp8 = t & 7;    // staging roles (unit = i*256+t)

  f32x4 acc[4];
#pragma unroll
  for (int j = 0; j < 4; j++) acc[j] = (f32x4){0.f, 0.f, 0.f, 0.f};

  short8b wreg[2], xreg[2];
  // prefetch chunk 0
#pragma unroll
  for (int i = 0; i < 2; i++) {
    int unit = i * 256 + t;
    int wr = unit >> 3, wp = unit & 7;
    wreg[i] = cvt8(w_red + wr * 256 + wp * 8);
    xreg[i] = cvt8(x + ((size_t)b << 20) + ((size_t)wr << 12) + px0 + wp * 8);
  }
  const unsigned pbase = (unsigned)(size_t)(&PL[0]);
  const unsigned vab = pbase + (unsigned)(lg * 256 + ln15 * 8);

  for (int ch = 0; ch < 4; ++ch) {
    __syncthreads();                            // prior MFMA LDS reads done
#pragma unroll
    for (int i = 0; i < 2; i++) {
      int unit = i * 256 + t;
      int kk = unit >> 3, ap = unit & 7;
      *(short8b*)&WL[kk * 72 + ap * 8] = wreg[i];
      int off = ((ap >> 1) << 10) + ((kk >> 2) << 6) + ((kk & 3) << 4) + (ap & 1) * 8;
      *(short8b*)&PL[off] = xreg[i];
    }
    __syncthreads();
    if (ch < 3) {                               // prefetch next chunk
      int c0 = (ch + 1) * 64;
#pragma unroll
      for (int i = 0; i < 2; i++) {
        int unit = i * 256 + t;
        int wr = unit >> 3, wp = unit & 7;
        wreg[i] = cvt8(w_red + wr * 256 + c0 + wp * 8);
        xreg[i] = cvt8(x + ((size_t)b << 20) + ((size_t)(c0 + wr) << 12) + px0 + wp * 8);
      }
    }
#pragma unroll
    for (int kstep = 0; kstep < 2; kstep++) {
      short8b am = *(const short8b*)&WL[(wv * 16 + ln15) * 72 + kstep * 32 + lg * 8];
      unsigned va0 = vab + kstep * 1024;
      unsigned va1 = va0 + 2048, va2 = va0 + 4096, va3 = va0 + 6144;
      uint2v q0, q1, q2, q3, q4, q5, q6, q7;
      TR_READ8(q0, q1, q2, q3, q4, q5, q6, q7, va0, va1, va2, va3);
      __builtin_amdgcn_sched_barrier(0);
      uint4v bu[4] = {(uint4v){q0.x, q0.y, q1.x, q1.y}, (uint4v){q2.x, q2.y, q3.x, q3.y},
                      (uint4v){q4.x, q4.y, q5.x, q5.y}, (uint4v){q6.x, q6.y, q7.x, q7.y}};
#pragma unroll
      for (int j = 0; j < 4; j++)
        acc[j] = __builtin_amdgcn_mfma_f32_16x16x32_bf16(
            am, __builtin_bit_cast(short8b, bu[j]), acc[j], 0, 0, 0);
    }
  }
  // epilogue: fp32 red (+bias) -> xs for R0; bf16 red -> red2
  __syncthreads();                              // MFMA phase done; reuse WL for preS
#pragma unroll
  for (int j = 0; j < 4; j++) {
    int pxl = j * 16 + ln15;
#pragma unroll
    for (int r = 0; r < 4; r++) {
      int m = wv * 16 + lg * 4 + r;
      float v = acc[j][r] + b_red[m];
      xs[m][pxl] = v;
      red2[((size_t)b << 18) + ((size_t)m << 12) + px0 + pxl] = bf16_rne(v);
    }
  }
  __syncthreads();
  float* preS = (float*)&WL[0];
  if (t < 192) {
    int j = t >> 6, px = t & 63;
    float a = b_wt[j];
    for (int kk = 0; kk < 64; kk++) a = fmaf(w_wt[j * 64 + kk], xs[kk][px], a);
    preS[j * 64 + px] = a;
  }
  __syncthreads();
  if (t < 64) {
    float s0 = 1.f / (1.f + __expf(-preS[t]));
    float s1 = 1.f / (1.f + __expf(-preS[64 + t]));
    float s2 = 1.f / (1.f + __expf(-preS[128 + t]));
    int w = t;   // px0 is a multiple of 64, tile = one image row
    float num = s1 + (w >= 1 ? s0 : 0.f) + (w <= 62 ? s2 : 0.f);
    R0[((size_t)b << 12) + px0 + t] = num / fmaxf(s0 + s1 + s2, 1e-6f);
  }
}

// MFMA u/lam: dst[b,m,px] = bf16( sum_k W[m,k]*red2[b,k,px] + bias[m] )
__global__ __launch_bounds__(256) void k_ulam(const unsigned short* __restrict__ red2,
    const unsigned short* __restrict__ wu2, const float* __restrict__ b_u,
    const unsigned short* __restrict__ wlam2, const float* __restrict__ b_lam,
    unsigned short* __restrict__ u, unsigned short* __restrict__ lam) {
  __shared__ __align__(16) unsigned short WL[256 * 72];  // [m][k 64 + pad 8]
  __shared__ __align__(16) unsigned short PL[4096];      // [pxb 4][kb4 16][4][16]
  const int t = threadIdx.x;
  const int px0 = blockIdx.x * 64;
  const int b = blockIdx.y;
  const int mt = blockIdx.z;
  const unsigned short* Wsrc = (mt == 0) ? wu2 : wlam2;
  const float* bias = (mt == 0) ? b_u : b_lam;
  unsigned short* dst = (mt == 0) ? u : lam;
  const unsigned short* red2b = red2 + ((size_t)b << 18);
  const int lane = t & 63;
  const int ln15 = lane & 15, lg = lane >> 4;
  const int ow = (t >> 6) * 64;                    // wave owns 64 m rows

#pragma unroll
  for (int i = 0; i < 8; i++) {
    int unit = i * 256 + t, wrow = unit >> 3, wp = unit & 7;
    *(short8b*)&WL[wrow * 72 + wp * 8] = *(const short8b*)(Wsrc + wrow * 64 + wp * 8);
  }
#pragma unroll
  for (int i = 0; i < 2; i++) {
    int unit = i * 256 + t, kk = unit >> 3, ap = unit & 7;
    int off = ((ap >> 1) << 10) + ((kk >> 2) << 6) + ((kk & 3) << 4) + (ap & 1) * 8;
    *(short8b*)&PL[off] = *(const short8b*)(red2b + (size_t)kk * 4096 + px0 + ap * 8);
  }
  __syncthreads();

  f32x4 acc[4][4];
#pragma unroll
  for (int i = 0; i < 4; i++)
#pragma unroll
    for (int j = 0; j < 4; j++) acc[i][j] = (f32x4){0.f, 0.f, 0.f, 0.f};

  const unsigned pbase = (unsigned)(size_t)(&PL[0]);
  const unsigned vab = pbase + (unsigned)(lg * 256 + ln15 * 8);
#pragma unroll
  for (int kstep = 0; kstep < 2; kstep++) {
    short8b am[4];
#pragma unroll
    for (int i = 0; i < 4; i++)
      am[i] = *(const short8b*)&WL[(ow + i * 16 + ln15) * 72 + kstep * 32 + lg * 8];
    unsigned va0 = vab + kstep * 1024;
    unsigned va1 = va0 + 2048, va2 = va0 + 4096, va3 = va0 + 6144;
    uint2v q0, q1, q2, q3, q4, q5, q6, q7;
    TR_READ8(q0, q1, q2, q3, q4, q5, q6, q7, va0, va1, va2, va3);
    __builtin_amdgcn_sched_barrier(0);
    uint4v bu[4] = {(uint4v){q0.x, q0.y, q1.x, q1.y}, (uint4v){q2.x, q2.y, q3.x, q3.y},
                    (uint4v){q4.x, q4.y, q5.x, q5.y}, (uint4v){q6.x, q6.y, q7.x, q7.y}};
#pragma unroll
    for (int i = 0; i < 4; i++)
#pragma unroll
      for (int j = 0; j < 4; j++)
        acc[i][j] = __builtin_amdgcn_mfma_f32_16x16x32_bf16(
            am[i], __builtin_bit_cast(short8b, bu[j]), acc[i][j], 0, 0, 0);
  }

#pragma unroll
  for (int i = 0; i < 4; i++) {
    int orow = ow + i * 16 + lg * 4;
    float bm[4];
#pragma unroll
    for (int r = 0; r < 4; r++) bm[r] = bias[orow + r];
#pragma unroll
    for (int j = 0; j < 4; j++) {
      int pxc = px0 + j * 16 + ln15;
#pragma unroll
      for (int r = 0; r < 4; r++)
        dst[((size_t)b << 20) + ((size_t)(orow + r) << 12) + pxc] =
            bf16_rne(acc[i][j][r] + bm[r]);
    }
  }
}

// chunk-parallel dual scan; block=(c,b), 256 thr = 64 r x 4 w-chunks
__global__ __launch_bounds__(256) void k_scan(const float* __restrict__ x,
    const unsigned short* __restrict__ lam, const unsigned short* __restrict__ u,
    const float* __restrict__ R0, unsigned short* __restrict__ P2,
    unsigned short* __restrict__ Q2) {
  __shared__ __align__(16) char smem[20224];
  float* lamS = (float*)smem;                 // [64][65] f32 (pass 1)
  unsigned* outS = (unsigned*)smem;           // 2 x [64][33] u32 (pass 2)
  float* fixS = (float*)(smem + 16896);       // [64][13] f32
  const int t = threadIdx.x;
  const int c = blockIdx.x;
  const int b = blockIdx.y;
  const size_t ibase = ((size_t)b << 20) + ((size_t)c << 12);

  {
    const unsigned short* lp = lam + ibase;
#pragma unroll
    for (int i = 0; i < 2; i++) {
      int unit = i * 256 + t;                 // 512 units of 8 ushorts
      int row = unit >> 3, c8 = unit & 7;
      short8b v = *(const short8b*)(lp + row * 64 + c8 * 8);
      float* d = &lamS[row * 65 + c8 * 8];
#pragma unroll
      for (int j = 0; j < 8; j++) d[j] = bf16_f((unsigned short)v[j]);
    }
  }
  const int r = t & 63;
  const int qc = __builtin_amdgcn_readfirstlane(t >> 6);  // w-chunk, wave-uniform
  float xr[16], R[16];
  {
    const float* xp = x + ibase + (r << 6) + (qc << 4);
    const float* rp = R0 + ((size_t)b << 12) + (r << 6) + (qc << 4);
#pragma unroll
    for (int i = 0; i < 4; i++) {
      float4 v = *(const float4*)(xp + i * 4);
      xr[i * 4] = v.x; xr[i * 4 + 1] = v.y; xr[i * 4 + 2] = v.z; xr[i * 4 + 3] = v.w;
      float4 w = *(const float4*)(rp + i * 4);
      R[i * 4] = w.x; R[i * 4 + 1] = w.y; R[i * 4 + 2] = w.z; R[i * 4 + 3] = w.w;
    }
  }
  __syncthreads();
  float g1[16], g2[16];
  float A = 1.f, B1 = 0.f, B2 = 0.f;
#pragma unroll
  for (int j = 0; j < 16; j++) {
    int w = (qc << 4) + j;
    float l1 = lamS[w * 65 + r];
    float l2 = lamS[(63 - w) * 65 + (63 - r)];
    g1[j] = l1 * xr[j];
    g2[j] = l2 * xr[j];
    A *= R[j];
    B1 = fmaf(B1, R[j], g1[j]);
    B2 = fmaf(B2, R[j], g2[j]);
  }
  __syncthreads();                       // lamS dead
  fixS[r * 13 + qc * 3 + 0] = A;
  fixS[r * 13 + qc * 3 + 1] = B1;
  fixS[r * 13 + qc * 3 + 2] = B2;
  __syncthreads();
  float h1 = 0.f, h2 = 0.f;
  for (int p = 0; p < qc; p++) {         // wave-uniform trip count
    float Ap  = fixS[r * 13 + p * 3 + 0];
    float Bp1 = fixS[r * 13 + p * 3 + 1];
    float Bp2 = fixS[r * 13 + p * 3 + 2];
    h1 = fmaf(h1, Ap, Bp1);
    h2 = fmaf(h2, Ap, Bp2);
  }
  float ur[16], fr[16];
  {
    const unsigned short* up = u + ibase + (r << 6) + (qc << 4);
    const unsigned short* fp = u + ibase + ((size_t)(63 - r) << 6) + (qc << 4);
    short8b u0 = *(const short8b*)(up);
    short8b u1 = *(const short8b*)(up + 8);
    short8b f0 = *(const short8b*)(fp);
    short8b f1 = *(const short8b*)(fp + 8);
#pragma unroll
    for (int j = 0; j < 8; j++) {
      ur[j] = bf16_f((unsigned short)u0[j]); ur[8 + j] = bf16_f((unsigned short)u1[j]);
      fr[j] = bf16_f((unsigned short)f0[j]); fr[8 + j] = bf16_f((unsigned short)f1[j]);
    }
  }
#pragma unroll
  for (int j2 = 0; j2 < 8; j2++) {
    int j = j2 * 2;
    h1 = fmaf(h1, R[j], g1[j]);         float p0 = h1 * ur[j];
    h2 = fmaf(h2, R[j], g2[j]);         float q0 = h2 * fr[j];
    h1 = fmaf(h1, R[j + 1], g1[j + 1]); float p1 = h1 * ur[j + 1];
    h2 = fmaf(h2, R[j + 1], g2[j + 1]); float q1 = h2 * fr[j + 1];
    int ob = r * 33 + (qc << 3) + j2;
    outS[ob]        = (unsigned)bf16_rne(p0) | ((unsigned)bf16_rne(p1) << 16);
    outS[2112 + ob] = (unsigned)bf16_rne(q0) | ((unsigned)bf16_rne(q1) << 16);
  }
  __syncthreads();
#pragma unroll
  for (int i = 0; i < 4; i++) {
    int flat4 = i * 256 + t;
    int s = flat4 >> 9;
    int rem = flat4 & 511;
    int row = rem >> 3, c8 = rem & 7;
    const unsigned* ls = &outS[s * 2112 + row * 33 + c8 * 4];
    uint4 v = make_uint4(ls[0], ls[1], ls[2], ls[3]);
    unsigned short* base = (s == 0) ? P2 : Q2;
    size_t off = ((size_t)(b * 256 + c)) * 4096 + row * 64 + c8 * 8;
    *(uint4*)(base + off) = v;
  }
}

// MFMA merge: out[b,o,px] = sum_{k'=0..511} W2T[o][k'] * A[k'][px] + b_merge[o]
__global__ __launch_bounds__(256) void k_merge(
    const unsigned short* __restrict__ P2, const unsigned short* __restrict__ Q2,
    const unsigned short* __restrict__ W2T, const float* __restrict__ b_merge,
    float* __restrict__ out) {
  __shared__ __align__(16) unsigned short WL[256 * 72];  // [o][k 64 + pad 8]
  __shared__ __align__(16) unsigned short PL[4096];      // [pxb 4][kb4 16][4][16]
  const int t = threadIdx.x;
  const int px0 = blockIdx.x * 64;
  const int b = blockIdx.y;
  const int lane = t & 63;
  const int ln15 = lane & 15, lg = lane >> 4;
  const int ow = (t >> 6) * 64;                    // wave owns 64 o rows

  const unsigned short* P2b = P2 + (size_t)b * 256 * 4096;
  const unsigned short* Q2b = Q2 + (size_t)b * 256 * 4096;

  f32x4 acc[4][4];
#pragma unroll
  for (int i = 0; i < 4; i++)
#pragma unroll
    for (int j = 0; j < 4; j++) acc[i][j] = (f32x4){0.f, 0.f, 0.f, 0.f};

  short8b wreg[8], preg[2];
#pragma unroll
  for (int i = 0; i < 8; i++) {
    int unit = i * 256 + t, wrow = unit >> 3, wp = unit & 7;
    wreg[i] = *(const short8b*)(W2T + (size_t)wrow * 512 + wp * 8);
  }
#pragma unroll
  for (int i = 0; i < 2; i++) {
    int unit = i * 256 + t, kk = unit >> 3, ap = unit & 7;
    preg[i] = *(const short8b*)(P2b + (size_t)kk * 4096 + px0 + ap * 8);
  }

  const unsigned pbase = (unsigned)(size_t)(&PL[0]);
  const unsigned vab = pbase + (unsigned)(lg * 256 + ln15 * 8);

  for (int it = 0; it < 8; ++it) {
    __syncthreads();
#pragma unroll
    for (int i = 0; i < 8; i++) {
      int unit = i * 256 + t, wrow = unit >> 3, wp = unit & 7;
      *(short8b*)&WL[wrow * 72 + wp * 8] = wreg[i];
    }
#pragma unroll
    for (int i = 0; i < 2; i++) {
      int unit = i * 256 + t, kk = unit >> 3, ap = unit & 7;
      int off = ((ap >> 1) << 10) + ((kk >> 2) << 6) + ((kk & 3) << 4) + (ap & 1) * 8;
      *(short8b*)&PL[off] = preg[i];
    }
    __syncthreads();
    if (it < 7) {
      int nt = it + 1;
#pragma unroll
      for (int i = 0; i < 8; i++) {
        int unit = i * 256 + t, wrow = unit >> 3, wp = unit & 7;
        wreg[i] = *(const short8b*)(W2T + (size_t)wrow * 512 + nt * 64 + wp * 8);
      }
      const unsigned short* ps = (nt < 4) ? P2b : Q2b;
      int row0 = (nt & 3) * 64;
#pragma unroll
      for (int i = 0; i < 2; i++) {
        int unit = i * 256 + t, kk = unit >> 3, ap = unit & 7;
        preg[i] = *(const short8b*)(ps + (size_t)(row0 + kk) * 4096 + px0 + ap * 8);
      }
    }
#pragma unroll
    for (int kstep = 0; kstep < 2; kstep++) {
      short8b am[4];
#pragma unroll
      for (int i = 0; i < 4; i++)
        am[i] = *(const short8b*)&WL[(ow + i * 16 + ln15) * 72 + kstep * 32 + lg * 8];
      unsigned va0 = vab + kstep * 1024;
      unsigned va1 = va0 + 2048, va2 = va0 + 4096, va3 = va0 + 6144;
      uint2v q0, q1, q2, q3, q4, q5, q6, q7;
      TR_READ8(q0, q1, q2, q3, q4, q5, q6, q7, va0, va1, va2, va3);
      __builtin_amdgcn_sched_barrier(0);
      uint4v bu[4] = {(uint4v){q0.x, q0.y, q1.x, q1.y}, (uint4v){q2.x, q2.y, q3.x, q3.y},
                      (uint4v){q4.x, q4.y, q5.x, q5.y}, (uint4v){q6.x, q6.y, q7.x, q7.y}};
#pragma unroll
      for (int i = 0; i < 4; i++)
#pragma unroll
        for (int j = 0; j < 4; j++)
          acc[i][j] = __builtin_amdgcn_mfma_f32_16x16x32_bf16(
              am[i], __builtin_bit_cast(short8b, bu[j]), acc[i][j], 0, 0, 0);
    }
  }

#pragma unroll
  for (int i = 0; i < 4; i++) {
    int orow = ow + i * 16 + lg * 4;
    float bm[4];
#pragma unroll
    for (int r = 0; r < 4; r++) bm[r] = b_merge[orow + r];
#pragma unroll
    for (int j = 0; j < 4; j++) {
      int pxc = px0 + j * 16 + ln15;
      float* op = out + ((size_t)b << 20) + ((size_t)orow << 12) + pxc;
#pragma unroll
      for (int r = 0; r < 4; r++) op[(size_t)r << 12] = acc[i][j][r] + bm[r];
    }
  }
}

extern "C" void kernel_launch(void* const* d_in, const int* in_sizes, int n_in,
                              void* d_out, int out_size, void* d_ws, size_t ws_size,
                              hipStream_t stream) {
  const float* x       = (const float*)d_in[0];
  const float* w_red   = (const float*)d_in[1];
  const float* b_red   = (const float*)d_in[2];
  const float* w_u     = (const float*)d_in[3];
  const float* b_u     = (const float*)d_in[4];
  const float* w_lam   = (const float*)d_in[5];
  const float* b_lam   = (const float*)d_in[6];
  const float* w_wt    = (const float*)d_in[7];
  const float* b_wt    = (const float*)d_in[8];
  const float* w_merge = (const float*)d_in[9];
  const float* b_merge = (const float*)d_in[10];
  float* out = (float*)d_out;
  char* wsb = (char*)d_ws;

  unsigned short* red2  = (unsigned short*)(wsb);            // 2097152 us
  unsigned short* u     = (unsigned short*)(wsb + 4194304);  // 8388608 us
  unsigned short* lam   = (unsigned short*)(wsb + 20971520); // 8388608 us
  float* R0             = (float*)(wsb + 37748736);          // 32768 f
  unsigned short* wu2   = (unsigned short*)(wsb + 37879808); // 16384 us
  unsigned short* wlam2 = (unsigned short*)(wsb + 37912576); // 16384 us
  unsigned short* W2T   = (unsigned short*)(wsb + 37945344); // 131072 us
  unsigned short* P2    = (unsigned short*)(wsb + 38207488); // 8388608 us
  unsigned short* Q2    = (unsigned short*)(wsb + 54984704); // 8388608 us (end ~72MB)

  hipLaunchKernelGGL(k_red,   dim3(72, 8),    dim3(256), 0, stream, x, w_red, b_red,
                     w_wt, b_wt, w_u, w_lam, w_merge, red2, R0, wu2, wlam2, W2T);
  hipLaunchKernelGGL(k_ulam,  dim3(64, 8, 2), dim3(256), 0, stream, red2, wu2, b_u,
                     wlam2, b_lam, u, lam);
  hipLaunchKernelGGL(k_scan,  dim3(256, 8),   dim3(256), 0, stream, x, lam, u, R0, P2, Q2);
  hipLaunchKernelGGL(k_merge, dim3(64, 8),    dim3(256), 0, stream, P2, Q2, W2T, b_merge, out);
}